// Round 10
// baseline (1190.926 us; speedup 1.0000x reference)
//
#include <hip/hip_runtime.h>

#define TT 512
#define BB 16
#define DD 256
#define HHH 128
#define GG 32
#define ZZ 8
#define RR_ 16
#define NAA 18

typedef _Float16 h2v __attribute__((ext_vector_type(2)));
typedef __attribute__((ext_vector_type(4))) float f4;
typedef __attribute__((ext_vector_type(4))) int i4;

__device__ __forceinline__ float sigmoid_(float x) { return 1.f / (1.f + __expf(-x)); }
__device__ __forceinline__ float tanh_(float x) { float e = __expf(2.f * x); return 1.f - 2.f / (e + 1.f); }
__device__ __forceinline__ float dot4(float4 a, float4 b) {
    return a.x * b.x + a.y * b.y + a.z * b.z + a.w * b.w;
}
__device__ __forceinline__ h2v u2h2(unsigned u) { union { unsigned u; h2v h; } c; c.u = u; return c.h; }

// Workgroup barrier WITHOUT the vmcnt(0) drain __syncthreads carries.
__device__ __forceinline__ void lds_barrier() {
    asm volatile("s_waitcnt lgkmcnt(0)" ::: "memory");
    __builtin_amdgcn_s_barrier();
}

// VALU-speed cross-lane add via DPP
template <int CTRL, int RM, int BM, bool BC>
__device__ __forceinline__ float dpp_add_f(float v) {
    return v + __int_as_float(__builtin_amdgcn_update_dpp(0, __float_as_int(v), CTRL, RM, BM, BC));
}
__device__ __forceinline__ float wave_sum_bcast(float p) {
    p = dpp_add_f<0x111, 0xf, 0xf, true>(p);
    p = dpp_add_f<0x112, 0xf, 0xf, true>(p);
    p = dpp_add_f<0x114, 0xf, 0xf, true>(p);
    p = dpp_add_f<0x118, 0xf, 0xf, true>(p);
    p = dpp_add_f<0x142, 0xa, 0xf, false>(p);
    p = dpp_add_f<0x143, 0xc, 0xf, false>(p);
    return __int_as_float(__builtin_amdgcn_readlane(__float_as_int(p), 63));
}
__device__ __forceinline__ float quad_sum(float v) {
    v = dpp_add_f<0xB1, 0xf, 0xf, true>(v);
    v = dpp_add_f<0x4E, 0xf, 0xf, true>(v);
    return v;
}
__device__ __forceinline__ float rdlane(float v, int l) {
    return __int_as_float(__builtin_amdgcn_readlane(__float_as_int(v), l));
}
__device__ __forceinline__ unsigned bperm_u(int byteaddr, unsigned src) {
    return (unsigned)__builtin_amdgcn_ds_bpermute(byteaddr, (int)src);
}
__device__ __forceinline__ float bperm_f(int byteaddr, float src) {
    return __int_as_float(__builtin_amdgcn_ds_bpermute(byteaddr, __float_as_int(src)));
}

// ---------------------------------------------------------------------------
// Generic tiled GEMM (256 thr): Out[p][n] (+)= bias[n] + A[p]·W[n]
// ---------------------------------------------------------------------------
__global__ __launch_bounds__(256) void gemm_k(
    const float* __restrict__ A, int K, const float* __restrict__ W, int ldw,
    const float* __restrict__ bias, float* __restrict__ Out, int ldout, int N, int accFlag)
{
    __shared__ float At[64][36];
    __shared__ float Wt[32][36];
    int row0 = blockIdx.x * 64, n0 = blockIdx.y * 32;
    int tid = threadIdx.x;
    int tx = tid & 15, ty = tid >> 4;
    float acc[4][2] = {};
    for (int k0 = 0; k0 < K; k0 += 32) {
        #pragma unroll
        for (int i = 0; i < 8; ++i) {
            int idx = tid + i * 256; int rr = idx >> 5, kk = idx & 31;
            At[rr][kk] = A[(size_t)(row0 + rr) * K + k0 + kk];
        }
        #pragma unroll
        for (int i = 0; i < 4; ++i) {
            int idx = tid + i * 256; int nn = idx >> 5, kk = idx & 31;
            Wt[nn][kk] = (n0 + nn < N) ? W[(size_t)(n0 + nn) * ldw + k0 + kk] : 0.f;
        }
        __syncthreads();
        #pragma unroll
        for (int kk = 0; kk < 32; kk += 4) {
            float4 w0 = *(const float4*)&Wt[tx][kk];
            float4 w1 = *(const float4*)&Wt[tx + 16][kk];
            #pragma unroll
            for (int rr = 0; rr < 4; ++rr) {
                float4 av = *(const float4*)&At[ty * 4 + rr][kk];
                acc[rr][0] += dot4(av, w0);
                acc[rr][1] += dot4(av, w1);
            }
        }
        __syncthreads();
    }
    #pragma unroll
    for (int cc = 0; cc < 2; ++cc) {
        int n = n0 + tx + cc * 16;
        if (n < N) {
            float badd = bias ? bias[n] : 0.f;
            #pragma unroll
            for (int rr = 0; rr < 4; ++rr) {
                int row = row0 + ty * 4 + rr;
                float v = acc[rr][cc] + badd;
                if (accFlag) Out[(size_t)row * ldout + n] += v;
                else         Out[(size_t)row * ldout + n] = v;
            }
        }
    }
}

// ---------------------------------------------------------------------------
// Both gi projections (fwd+bwd) + weight pack in ONE launch: grid (128, 25).
// ---------------------------------------------------------------------------
__global__ __launch_bounds__(256) void gemm_gi(
    const float* __restrict__ A,
    const float* __restrict__ wf, const float* __restrict__ bf, float* __restrict__ of,
    const float* __restrict__ wb, const float* __restrict__ bb, float* __restrict__ ob,
    const float* __restrict__ whf, const float* __restrict__ whb,
    const float* __restrict__ whe,
    unsigned* __restrict__ pk, unsigned* __restrict__ pk_e)
{
    int y = blockIdx.y;
    if (y == 24) {
        for (int i = blockIdx.x * 256 + threadIdx.x; i < 50688; i += 32768) {
            if (i < 49152) {
                int dir = i / 24576; int r = i % 24576;
                int w = r / 3072;    int r2 = r % 3072;
                int T = r2 / 1024;   int r3 = r2 % 1024;
                int kt = r3 / 256;   int r4 = r3 % 256;
                int lane = r4 / 4;   int jd = r4 % 4;
                const float* wsrc = dir ? whb : whf;
                int row = T * 128 + 16 * w + (lane & 15);
                int k0 = kt * 32 + (lane >> 4) * 8 + 2 * jd;
                union { _Float16 h[2]; unsigned u; } c;
                c.h[0] = (_Float16)wsrc[row * 128 + k0];
                c.h[1] = (_Float16)wsrc[row * 128 + k0 + 1];
                pk[i] = c.u;
            } else {
                int ie = i - 49152;
                int s = ie / 384;  int rem = ie % 384;
                int k = rem / 12;  int e = rem % 12;
                int j = e / 4;     int m = e % 4;
                int row = j * 32 + k, k0 = 8 * s + 2 * m;
                union { _Float16 h[2]; unsigned u; } c;
                c.h[0] = (_Float16)whe[row * 32 + k0];
                c.h[1] = (_Float16)whe[row * 32 + k0 + 1];
                pk_e[ie] = c.u;
            }
        }
        return;
    }

    __shared__ float At[64][36];
    __shared__ float Wt[32][36];
    const float* W; const float* bias; float* Out; int n0;
    if (y < 12) { W = wf; bias = bf; Out = of; n0 = y * 32; }
    else        { W = wb; bias = bb; Out = ob; n0 = (y - 12) * 32; }
    int row0 = blockIdx.x * 64;
    int tid = threadIdx.x;
    int tx = tid & 15, ty = tid >> 4;
    float acc[4][2] = {};
    for (int k0 = 0; k0 < 256; k0 += 32) {
        #pragma unroll
        for (int i = 0; i < 8; ++i) {
            int idx = tid + i * 256; int rr = idx >> 5, kk = idx & 31;
            At[rr][kk] = A[(size_t)(row0 + rr) * 256 + k0 + kk];
        }
        #pragma unroll
        for (int i = 0; i < 4; ++i) {
            int idx = tid + i * 256; int nn = idx >> 5, kk = idx & 31;
            Wt[nn][kk] = W[(size_t)(n0 + nn) * 256 + k0 + kk];
        }
        __syncthreads();
        #pragma unroll
        for (int kk = 0; kk < 32; kk += 4) {
            float4 w0 = *(const float4*)&Wt[tx][kk];
            float4 w1 = *(const float4*)&Wt[tx + 16][kk];
            #pragma unroll
            for (int rr = 0; rr < 4; ++rr) {
                float4 av = *(const float4*)&At[ty * 4 + rr][kk];
                acc[rr][0] += dot4(av, w0);
                acc[rr][1] += dot4(av, w1);
            }
        }
        __syncthreads();
    }
    #pragma unroll
    for (int cc = 0; cc < 2; ++cc) {
        int n = n0 + tx + cc * 16;
        float badd = bias[n];
        #pragma unroll
        for (int rr = 0; rr < 4; ++rr) {
            int row = row0 + ty * 4 + rr;
            Out[(size_t)row * 384 + n] = acc[rr][cc] + badd;
        }
    }
}

// ---------------------------------------------------------------------------
// Fused dispatch (256 thr/block): blocks 0-31 = GRU scan (4-wave form),
// blocks 32-415 = gie tiles; 416-671 = swe tiles.
// ---------------------------------------------------------------------------
struct __align__(16) SmGru { _Float16 hb[2][128]; };
struct __align__(16) SmGemm { float At[64][36]; float Wt[32][36]; };
union __align__(16) SmU { SmGru g; SmGemm m; };

__device__ __forceinline__ void gemm_tile256(
    const float* __restrict__ A, int K, const float* __restrict__ W, int ldw,
    const float* __restrict__ bias, float* __restrict__ Out, int ldout, int N,
    int row0, int n0, SmGemm& sm)
{
    int tid = threadIdx.x;
    int tx = tid & 15, ty = tid >> 4;
    float acc[4][2] = {};
    for (int k0 = 0; k0 < K; k0 += 32) {
        #pragma unroll
        for (int i = 0; i < 8; ++i) {
            int idx = tid + i * 256; int rr = idx >> 5, kk = idx & 31;
            sm.At[rr][kk] = A[(size_t)(row0 + rr) * K + k0 + kk];
        }
        #pragma unroll
        for (int i = 0; i < 4; ++i) {
            int idx = tid + i * 256; int nn = idx >> 5, kk = idx & 31;
            sm.Wt[nn][kk] = (n0 + nn < N) ? W[(size_t)(n0 + nn) * ldw + k0 + kk] : 0.f;
        }
        __syncthreads();
        #pragma unroll
        for (int kk = 0; kk < 32; kk += 4) {
            float4 w0 = *(const float4*)&sm.Wt[tx][kk];
            float4 w1 = *(const float4*)&sm.Wt[tx + 16][kk];
            #pragma unroll
            for (int rr = 0; rr < 4; ++rr) {
                float4 av = *(const float4*)&sm.At[ty * 4 + rr][kk];
                acc[rr][0] += dot4(av, w0);
                acc[rr][1] += dot4(av, w1);
            }
        }
        __syncthreads();
    }
    #pragma unroll
    for (int cc = 0; cc < 2; ++cc) {
        int n = n0 + tx + cc * 16;
        if (n < N) {
            float badd = bias[n];
            #pragma unroll
            for (int rr = 0; rr < 4; ++rr)
                Out[(size_t)(row0 + ty * 4 + rr) * ldout + n] = acc[rr][cc] + badd;
        }
    }
}

__global__ __launch_bounds__(256, 2) void gru_fused(
    const float* __restrict__ gi_f, const float* __restrict__ gi_b,
    const unsigned* __restrict__ pk,
    const float* __restrict__ bhh_f, const float* __restrict__ bhh_b,
    float* __restrict__ s_seq,
    const float* __restrict__ e,
    const float* __restrict__ wih_e, const float* __restrict__ bih_e, float* __restrict__ gie,
    const float* __restrict__ sw1_w, const float* __restrict__ sw1_b, float* __restrict__ swe)
{
    __shared__ SmU sm;
    int bx = blockIdx.x;
    if (bx >= 416) {
        int t = bx - 416;
        gemm_tile256(e, 256, sw1_w, 296, sw1_b, swe, 64, 64, (t & 127) * 64, (t >> 7) * 32, sm.m);
        return;
    }
    if (bx >= 32) {
        int t = bx - 32;
        gemm_tile256(e, 256, wih_e, 512, bih_e, gie, 96, 96, (t & 127) * 64, (t >> 7) * 32, sm.m);
        return;
    }

    // ---------------- GRU (MFMA body, 4-wave form) ----------------
    int dir = bx >> 4, b = bx & 15;
    const float* gi  = dir ? gi_b  : gi_f;
    const float* bhh = dir ? bhh_b : bhh_f;
    int tid = threadIdx.x;
    int w = tid >> 6;          // 0..3
    int lane = tid & 63;
    int quad = lane >> 4;
    int j = 32 * w + (lane & 31);   // epilogue j (valid for lane<32)

    i4 bf[2][3][4];
    #pragma unroll
    for (int tt = 0; tt < 2; ++tt)
        #pragma unroll
        for (int T = 0; T < 3; ++T)
            #pragma unroll
            for (int kt = 0; kt < 4; ++kt)
                bf[tt][T][kt] = *(const i4*)(pk + (size_t)((((dir * 8 + 2 * w + tt) * 3 + T) * 4 + kt) * 64 + lane) * 4);
    #pragma unroll
    for (int tt = 0; tt < 2; ++tt)
        #pragma unroll
        for (int T = 0; T < 3; ++T)
            #pragma unroll
            for (int kt = 0; kt < 4; ++kt)
                asm volatile("" : "+a"(bf[tt][T][kt]));

    if (tid < 128) sm.g.hb[0][tid] = (_Float16)0.f;

    float bhr = 0.f, bhz = 0.f, bhn = 0.f;
    float gra = 0.f, gza = 0.f, gna = 0.f;
    float grb = 0.f, gzb = 0.f, gnb = 0.f;
    float hreg = 0.f;
    if (lane < 32) {
        bhr = bhh[j]; bhz = bhh[128 + j]; bhn = bhh[256 + j];
        int t0 = dir ? 511 : 0;
        int t1 = dir ? 510 : 1;
        size_t p0 = (size_t)(b * TT + t0) * 384;
        size_t p1 = (size_t)(b * TT + t1) * 384;
        gra = gi[p0 + j]; gza = gi[p0 + 128 + j]; gna = gi[p0 + 256 + j];
        grb = gi[p1 + j]; gzb = gi[p1 + 128 + j]; gnb = gi[p1 + 256 + j];
    }
    __syncthreads();

    int cur = 0;
    auto body = [&](int step, float& gr, float& gz, float& gn) {
        i4 af[4];
        #pragma unroll
        for (int kt = 0; kt < 4; ++kt)
            af[kt] = *(const i4*)(&sm.g.hb[cur][kt * 32 + quad * 8]);
        f4 accr0 = {0.f, 0.f, 0.f, 0.f}, accr1 = {0.f, 0.f, 0.f, 0.f};
        f4 accz0 = {0.f, 0.f, 0.f, 0.f}, accz1 = {0.f, 0.f, 0.f, 0.f};
        f4 accn0 = {0.f, 0.f, 0.f, 0.f}, accn1 = {0.f, 0.f, 0.f, 0.f};
        asm volatile("s_nop 3" : "+v"(accr0), "+v"(accz0), "+v"(accn0),
                                 "+v"(accr1), "+v"(accz1), "+v"(accn1));
        #pragma unroll
        for (int kt = 0; kt < 4; ++kt) {
            asm volatile("v_mfma_f32_16x16x32_f16 %0, %1, %2, %0" : "+v"(accr0) : "v"(af[kt]), "a"(bf[0][0][kt]));
            asm volatile("v_mfma_f32_16x16x32_f16 %0, %1, %2, %0" : "+v"(accz0) : "v"(af[kt]), "a"(bf[0][1][kt]));
            asm volatile("v_mfma_f32_16x16x32_f16 %0, %1, %2, %0" : "+v"(accn0) : "v"(af[kt]), "a"(bf[0][2][kt]));
            asm volatile("v_mfma_f32_16x16x32_f16 %0, %1, %2, %0" : "+v"(accr1) : "v"(af[kt]), "a"(bf[1][0][kt]));
            asm volatile("v_mfma_f32_16x16x32_f16 %0, %1, %2, %0" : "+v"(accz1) : "v"(af[kt]), "a"(bf[1][1][kt]));
            asm volatile("v_mfma_f32_16x16x32_f16 %0, %1, %2, %0" : "+v"(accn1) : "v"(af[kt]), "a"(bf[1][2][kt]));
        }
        asm volatile("s_nop 7\n\ts_nop 7" : "+v"(accr0), "+v"(accz0), "+v"(accn0),
                                            "+v"(accr1), "+v"(accz1), "+v"(accn1));
        if (lane < 32) {
            int t = dir ? (511 - step) : step;
            int p = b * TT + t;
            bool hi = lane >= 16;
            float ar = hi ? accr1[0] : accr0[0];
            float az = hi ? accz1[0] : accz0[0];
            float an = hi ? accn1[0] : accn0[0];
            float r = sigmoid_(gr + bhr + ar);
            float z = sigmoid_(gz + bhz + az);
            float n = tanh_(gn + r * (bhn + an));
            float hn = (1.f - z) * n + z * hreg;
            hreg = hn;
            sm.g.hb[cur ^ 1][j] = (_Float16)hn;
            s_seq[(size_t)p * 256 + dir * 128 + j] = hn;
            int s2 = step + 2;
            int tp = (s2 < 512) ? (dir ? (511 - s2) : s2) : t;
            size_t p2 = (size_t)(b * TT + tp) * 384;
            gr = gi[p2 + j]; gz = gi[p2 + 128 + j]; gn = gi[p2 + 256 + j];
        }
        lds_barrier();
        cur ^= 1;
    };

    for (int step = 0; step < 512; step += 2) {
        body(step,     gra, gza, gna);
        body(step + 1, grb, gzb, gnb);
    }
}

// ---------------------------------------------------------------------------
// Fused controller, 16-step phases (33 barriers).
//  - producer keeps h REPLICATED IN REGISTERS (16 f16x2/lane); per-step
//    redistribution via ds_bpermute (LDS crossbar, ~30cy) instead of the
//    ds_write->lgkmcnt->ds_read round-trip (~120-240cy). Ring writes (hb/hf)
//    remain for the consumer but are OFF the producer's serial path.
//  - consumer u-decoupling: hid depends on z only through u = wz.z, and
//    u_t = beta*(wz.cand) + (1-beta)*u_{t-1} -- the az-dot and z-vector
//    update leave the serial chain (z maintained off-path for output).
// ---------------------------------------------------------------------------
__global__ __launch_bounds__(128, 1) void ctrl_fused(
    const float* __restrict__ gie, const unsigned* __restrict__ pk_e,
    const float* __restrict__ bhh_e,
    const float* __restrict__ mu_w, const float* __restrict__ mu_b,
    const float* __restrict__ lv_w, const float* __restrict__ lv_b,
    const float* __restrict__ sw1_w, const float* __restrict__ sw2_w,
    const float* __restrict__ sw2_b,
    const float* __restrict__ swe,      // hid_pre e-part (B*T, 64)
    const float* __restrict__ eps,      // (B*T, 8)
    float* __restrict__ out_mu, float* __restrict__ out_lv,
    float* __restrict__ beta_o, float* __restrict__ z_o)
{
    int b = blockIdx.x;
    int tid = threadIdx.x;
    int wid = tid >> 6;
    int lane = tid & 63;
    int pbase = b * TT;

    __shared__ __align__(16) _Float16 hb[32][32];   // f16 ring (consumer-facing)
    __shared__ __align__(16) float    hf[32][32];   // f32 ring (consumer math)

    // ---- producer state (wave 0): register-replicated h ----
    int j = lane & 31, half = lane >> 5;
    unsigned wA[16], wB[8];
    unsigned hx[16];
    #pragma unroll
    for (int m = 0; m < 16; ++m) hx[m] = 0u;
    float bhr = 0.f, bhz = 0.f, bhn = 0.f, hreg = 0.f;
    float g1[16] = {}, g2[16] = {}, g3[16] = {};
    if (wid == 0) {
        // wA: full-K weights for gate (half==0 ? r : z), row j.
        // wA[4s+m] = pk_e[(s*32+j)*12 + half*4 + m]  (pairs K=8s+2m..+1 == hx[4s+m])
        #pragma unroll
        for (int s = 0; s < 4; ++s) {
            const uint4* wp = (const uint4*)(pk_e + (size_t)(s * 32 + j) * 12 + half * 4);
            uint4 u = *wp;
            wA[4 * s + 0] = u.x; wA[4 * s + 1] = u.y; wA[4 * s + 2] = u.z; wA[4 * s + 3] = u.w;
        }
        // wB: n-gate half-K (half==0 -> K 0..15 (s=0,1); half==1 -> K 16..31 (s=2,3))
        #pragma unroll
        for (int si = 0; si < 2; ++si) {
            int s = half ? (2 + si) : si;
            const uint4* wp = (const uint4*)(pk_e + (size_t)(s * 32 + j) * 12 + 8);
            uint4 u = *wp;
            wB[4 * si + 0] = u.x; wB[4 * si + 1] = u.y; wB[4 * si + 2] = u.z; wB[4 * si + 3] = u.w;
        }
        if (lane < 32) {
            bhr = bhh_e[j]; bhz = bhh_e[32 + j]; bhn = bhh_e[64 + j];
            #pragma unroll
            for (int i = 0; i < 16; ++i) {
                size_t p = (size_t)(pbase + i) * 96;
                g1[i] = gie[p + j]; g2[i] = gie[p + 32 + j]; g3[i] = gie[p + 64 + j];
            }
        }
    }

    // ---- consumer state (wave 1) ----
    int x = lane >> 3, kind = (lane >> 2) & 1, s = lane & 3;
    float4 swh4[8];
    float4 wz0v = {0,0,0,0}, wz1v = {0,0,0,0}, mlw0 = {0,0,0,0}, mlw1 = {0,0,0,0};
    float w2 = 0.f, sb2 = 0.f, mlb = 0.f;
    float4 zr0 = {0.f, 0.f, 0.f, 0.f}, zr1 = {0.f, 0.f, 0.f, 0.f};
    float ureg = 0.f;       // wz . z  (serial scalar; replaces az dot)
    float hp[16] = {}, ep[16] = {};
    if (wid == 1) {
        #pragma unroll
        for (int i = 0; i < 8; ++i)
            swh4[i] = *(const float4*)(sw1_w + (size_t)lane * 296 + 256 + 4 * i);
        wz0v = *(const float4*)(sw1_w + (size_t)lane * 296 + 288);
        wz1v = *(const float4*)(sw1_w + (size_t)lane * 296 + 292);
        w2 = sw2_w[lane];
        sb2 = sw2_b[0];
        const float* mw = kind ? lv_w : mu_w;
        mlw0 = *(const float4*)(mw + x * 32 + 8 * s);
        mlw1 = *(const float4*)(mw + x * 32 + 8 * s + 4);
        mlb = kind ? lv_b[x] : mu_b[x];
        #pragma unroll
        for (int i = 0; i < 16; ++i) {
            hp[i] = swe[(size_t)(pbase + i) * 64 + lane];
            ep[i] = eps[(size_t)(pbase + i) * 8 + x];
        }
    }
    __syncthreads();

    int xaddr = (lane ^ 32) << 2;    // cross-half bpermute address (bytes)

    auto prod_step = [&](int t, float& ga, float& gb, float& gc) {
        // dots from register-held h (no LDS on the serial path)
        float dA0 = 0.f, dA1 = 0.f, dB = 0.f;
        #pragma unroll
        for (int m = 0; m < 8; ++m) {
            dA0 = __builtin_amdgcn_fdot2(u2h2(wA[m]),     u2h2(hx[m]),     dA0, false);
            dA1 = __builtin_amdgcn_fdot2(u2h2(wA[8 + m]), u2h2(hx[8 + m]), dA1, false);
        }
        int hoff = half ? 8 : 0;
        #pragma unroll
        for (int m = 0; m < 8; ++m)
            dB = __builtin_amdgcn_fdot2(u2h2(wB[m]), u2h2(hx[hoff + m]), dB, false);
        float dA = dA0 + dA1;
        // cross-half exchange: half0 gets z-dot, both get the other n-half
        float oA = bperm_f(xaddr, dA);
        float oB = bperm_f(xaddr, dB);
        float an = dB + oB;
        unsigned packed = 0u;
        if (lane < 32) {
            float r = sigmoid_(ga + bhr + dA);
            float z = sigmoid_(gb + bhz + oA);
            float n = tanh_(gc + r * (bhn + an));
            float hn = (1.f - z) * n + z * hreg;
            hreg = hn;
            hb[t & 31][j] = (_Float16)hn;    // consumer-facing (off serial path)
            hf[t & 31][j] = hn;
            // pack pair (even lane 2m packs h_{2m},h_{2m+1})
            float hn_o = __int_as_float(__builtin_amdgcn_update_dpp(
                0, __float_as_int(hn), 0xB1, 0xf, 0xf, true));
            packed = __builtin_bit_cast(unsigned, __builtin_amdgcn_cvt_pkrtz(hn, hn_o));
            int t16 = (t + 16 < 512) ? (t + 16) : t;
            size_t p2 = (size_t)(pbase + t16) * 96;
            ga = gie[p2 + j]; gb = gie[p2 + 32 + j]; gc = gie[p2 + 64 + j];
        }
        // redistribute: hx[m] <- packed value of lane 2m (broadcast to all)
        #pragma unroll
        for (int m = 0; m < 16; ++m)
            hx[m] = bperm_u(m * 8, packed);
    };

    auto cons_step = [&](int t, float& hpi, float& epi) {
        int sl = t & 31;
        const float4* hv4 = (const float4*)(&hf[sl][0]);
        float4 h0 = hv4[0], h1 = hv4[1], h2 = hv4[2], h3 = hv4[3];
        float4 h4 = hv4[4], h5 = hv4[5], h6 = hv4[6], h7 = hv4[7];
        float d0 = dot4(swh4[0], h0) + dot4(swh4[1], h1);
        float d1 = dot4(swh4[2], h2) + dot4(swh4[3], h3);
        float d2 = dot4(swh4[4], h4) + dot4(swh4[5], h5);
        float d3 = dot4(swh4[6], h6) + dot4(swh4[7], h7);
        float hsum = (d0 + d1) + (d2 + d3);
        float4 hs0 = *(const float4*)(&hf[sl][8 * s]);
        float4 hs1 = *(const float4*)(&hf[sl][8 * s + 4]);
        float pacc = quad_sum(dot4(mlw0, hs0) + dot4(mlw1, hs1));
        float v = pacc + mlb;
        float other = __int_as_float(__builtin_amdgcn_ds_swizzle(__float_as_int(v), 0x101F)); // xor 4
        float muv = kind ? other : v;
        float lvv = kind ? v : other;
        float cand = muv + __expf(0.5f * lvv) * epi;
        float sc0 = rdlane(cand, 0),  sc1 = rdlane(cand, 8);
        float sc2 = rdlane(cand, 16), sc3 = rdlane(cand, 24);
        float sc4 = rdlane(cand, 32), sc5 = rdlane(cand, 40);
        float sc6 = rdlane(cand, 48), sc7 = rdlane(cand, 56);
        // z-independent: candidate dot with wz (for the u recurrence)
        float candd = wz0v.x * sc0 + wz0v.y * sc1 + wz0v.z * sc2 + wz0v.w * sc3
                    + wz1v.x * sc4 + wz1v.y * sc5 + wz1v.z * sc6 + wz1v.w * sc7;
        // serial chain: a -> hid -> beta -> u
        float a = (hpi + hsum) + ureg;
        float hid = tanh_(a);
        float beta = sigmoid_(wave_sum_bcast(w2 * hid) + sb2);
        float omb = 1.f - beta;
        ureg = beta * candd + omb * ureg;
        // z vector maintained off the serial path (output only)
        zr0.x = beta * sc0 + omb * zr0.x; zr0.y = beta * sc1 + omb * zr0.y;
        zr0.z = beta * sc2 + omb * zr0.z; zr0.w = beta * sc3 + omb * zr0.w;
        zr1.x = beta * sc4 + omb * zr1.x; zr1.y = beta * sc5 + omb * zr1.y;
        zr1.z = beta * sc6 + omb * zr1.z; zr1.w = beta * sc7 + omb * zr1.w;
        int p = pbase + t;
        if (lane == 0) {
            beta_o[p] = beta;
            *(float4*)(z_o + (size_t)p * 8)     = zr0;
            *(float4*)(z_o + (size_t)p * 8 + 4) = zr1;
        }
        if ((lane & 7) == 0) out_mu[(size_t)p * 8 + x] = muv;
        if ((lane & 7) == 4) out_lv[(size_t)p * 8 + x] = lvv;
        int t16 = (t + 16 < 512) ? (t + 16) : t;
        hpi = swe[(size_t)(pbase + t16) * 64 + lane];
        epi = eps[(size_t)(pbase + t16) * 8 + x];
    };

    // 33 phases: producer active in 0..31, consumer in 1..32 (lags 1 phase)
    for (int ph = 0; ph < 33; ++ph) {
        if (wid == 0) {
            if (ph < 32) {
                int t0 = ph * 16;
                #pragma unroll
                for (int i = 0; i < 16; ++i)
                    prod_step(t0 + i, g1[i], g2[i], g3[i]);
            }
        } else {
            if (ph >= 1) {
                int t0 = (ph - 1) * 16;
                #pragma unroll
                for (int i = 0; i < 16; ++i)
                    cons_step(t0 + i, hp[i], ep[i]);
            }
        }
        lds_barrier();
    }
}

// ---------------------------------------------------------------------------
// Decoder hypernet + rank-R perturbation + LayerNorm + head. P=8/WG.
// ---------------------------------------------------------------------------
__global__ __launch_bounds__(256, 3) void decoder_final(
    const float* __restrict__ e_seq, const float* __restrict__ z_o,
    const float* __restrict__ dec1_w, const float* __restrict__ dec1_b,
    const float* __restrict__ dec2_w, const float* __restrict__ dec2_b,
    const float* __restrict__ ln_g, const float* __restrict__ ln_b,
    const float* __restrict__ head_w, const float* __restrict__ head_b,
    float* __restrict__ logits)
{
    __shared__ __align__(16) float e_l[8][256];
    __shared__ __align__(16) float hmid[8][32];
    __shared__ float zl[8][8];
    __shared__ float tmpw[8][16];
    __shared__ __align__(16) float partb[2048];
    __shared__ float red1[8][16];
    __shared__ float red2[8][16];
    __shared__ float stats[8][2];
    int tid = threadIdx.x;
    int p0 = blockIdx.x * 8;

    {
        const float4* eg = (const float4*)(e_seq + (size_t)p0 * 256);
        float4* el4 = (float4*)&e_l[0][0];
        el4[tid] = eg[tid];
        el4[tid + 256] = eg[tid + 256];
        if (tid < 64) ((float*)zl)[tid] = z_o[p0 * 8 + tid];
    }
    __syncthreads();
    {
        int pp = tid >> 5, g = tid & 31;
        float a = dec1_b[g];
        #pragma unroll
        for (int x = 0; x < 8; ++x) a += dec1_w[g * 8 + x] * zl[pp][x];
        hmid[pp][g] = tanh_(a);
    }
    __syncthreads();
    // ---- pass B: tmp[pp][r] = sum_d Bm[d,r]*e[d]
    {
        int r = tid & 15, dgrp = tid >> 4;
        float acc[8];
        #pragma unroll
        for (int pp = 0; pp < 8; ++pp) acc[pp] = 0.f;
        for (int iblk = 0; iblk < 8; ++iblk) {
            float4 wr[2][8]; float wb[2]; int dd[2];
            #pragma unroll
            for (int ii = 0; ii < 2; ++ii) {
                int d = dgrp + 16 * (iblk * 2 + ii);
                dd[ii] = d;
                int row = 4096 + d * 16 + r;
                const float4* wp = (const float4*)(dec2_w + (size_t)row * 32);
                #pragma unroll
                for (int g = 0; g < 8; ++g) wr[ii][g] = wp[g];
                wb[ii] = dec2_b[row];
            }
            #pragma unroll 1
            for (int pp = 0; pp < 8; ++pp) {
                const float4* hv = (const float4*)hmid[pp];
                float b0 = wb[0], b1 = wb[1];
                #pragma unroll
                for (int g = 0; g < 8; ++g) {
                    float4 hh = hv[g];
                    b0 += dot4(wr[0][g], hh);
                    b1 += dot4(wr[1][g], hh);
                }
                acc[pp] += b0 * e_l[pp][dd[0]] + b1 * e_l[pp][dd[1]];
            }
        }
        #pragma unroll
        for (int pp = 0; pp < 8; ++pp) partb[(pp * 16 + r) * 16 + dgrp] = acc[pp];
    }
    __syncthreads();
    if (tid < 128) {
        int pp = tid >> 4, rr = tid & 15;
        float s = 0.f;
        #pragma unroll
        for (int dg = 0; dg < 16; ++dg) s += partb[(pp * 16 + rr) * 16 + dg];
        tmpw[pp][rr] = s;
    }
    __syncthreads();
    // ---- pass A
    {
        int d = tid;
        float po[8];
        #pragma unroll
        for (int pp = 0; pp < 8; ++pp) po[pp] = e_l[pp][d];
        for (int rblk = 0; rblk < 8; ++rblk) {
            float4 wr[2][8]; float wb[2];
            #pragma unroll
            for (int ii = 0; ii < 2; ++ii) {
                int row = d * 16 + rblk * 2 + ii;
                const float4* wp = (const float4*)(dec2_w + (size_t)row * 32);
                #pragma unroll
                for (int g = 0; g < 8; ++g) wr[ii][g] = wp[g];
                wb[ii] = dec2_b[row];
            }
            #pragma unroll 1
            for (int pp = 0; pp < 8; ++pp) {
                const float4* hv = (const float4*)hmid[pp];
                float a0 = wb[0], a1 = wb[1];
                #pragma unroll
                for (int g = 0; g < 8; ++g) {
                    float4 hh = hv[g];
                    a0 += dot4(wr[0][g], hh);
                    a1 += dot4(wr[1][g], hh);
                }
                po[pp] += a0 * tmpw[pp][rblk * 2] + a1 * tmpw[pp][rblk * 2 + 1];
            }
        }
        #pragma unroll
        for (int pp = 0; pp < 8; ++pp) partb[pp * 256 + d] = po[pp];
    }
    __syncthreads();
    if (tid < 128) {
        int pp = tid >> 4, c = tid & 15;
        float s = 0.f, s2 = 0.f;
        #pragma unroll
        for (int i = 0; i < 16; ++i) { float v = partb[pp * 256 + c * 16 + i]; s += v; s2 += v * v; }
        red1[pp][c] = s; red2[pp][c] = s2;
    }
    __syncthreads();
    if (tid < 8) {
        float s = 0.f, s2 = 0.f;
        #pragma unroll
        for (int c = 0; c < 16; ++c) { s += red1[tid][c]; s2 += red2[tid][c]; }
        float mean = s * (1.f / 256.f);
        float var = s2 * (1.f / 256.f) - mean * mean;
        stats[tid][0] = mean;
        stats[tid][1] = rsqrtf(var + 1e-5f);
    }
    __syncthreads();
    {
        int d = tid;
        float g = ln_g[d], bln = ln_b[d];
        #pragma unroll
        for (int pp = 0; pp < 8; ++pp) {
            float v = (partb[pp * 256 + d] - stats[pp][0]) * stats[pp][1];
            partb[pp * 256 + d] = v * g + bln;
        }
    }
    __syncthreads();
    if (tid < 144) {
        int pp = tid / 18, na = tid - pp * 18;
        float a = head_b[na];
        for (int d2 = 0; d2 < 256; ++d2)
            a += partb[pp * 256 + d2] * head_w[na * 256 + d2];
        logits[(size_t)(p0 + pp) * 18 + na] = a;
    }
}

// ---------------------------------------------------------------------------
extern "C" void kernel_launch(void* const* d_in, const int* in_sizes, int n_in,
                              void* d_out, int out_size, void* d_ws, size_t ws_size,
                              hipStream_t stream) {
    (void)in_sizes; (void)n_in; (void)out_size; (void)ws_size;
    const float* e     = (const float*)d_in[0];
    const float* eps   = (const float*)d_in[1];
    const float* wih_f = (const float*)d_in[2];
    const float* whh_f = (const float*)d_in[3];
    const float* bih_f = (const float*)d_in[4];
    const float* bhh_f = (const float*)d_in[5];
    const float* wih_b = (const float*)d_in[6];
    const float* whh_b = (const float*)d_in[7];
    const float* bih_b = (const float*)d_in[8];
    const float* bhh_b = (const float*)d_in[9];
    const float* wih_e = (const float*)d_in[10];
    const float* whh_e = (const float*)d_in[11];
    const float* bih_e = (const float*)d_in[12];
    const float* bhh_e = (const float*)d_in[13];
    const float* mu_w  = (const float*)d_in[14];
    const float* mu_b  = (const float*)d_in[15];
    const float* lv_w  = (const float*)d_in[16];
    const float* lv_b  = (const float*)d_in[17];
    const float* sw1_w = (const float*)d_in[18];
    const float* sw1_b = (const float*)d_in[19];
    const float* sw2_w = (const float*)d_in[20];
    const float* sw2_b = (const float*)d_in[21];
    const float* dec1_w = (const float*)d_in[22];
    const float* dec1_b = (const float*)d_in[23];
    const float* dec2_w = (const float*)d_in[24];
    const float* dec2_b = (const float*)d_in[25];
    const float* ln_g  = (const float*)d_in[26];
    const float* ln_b  = (const float*)d_in[27];
    const float* head_w = (const float*)d_in[28];
    const float* head_b = (const float*)d_in[29];

    float* ws    = (float*)d_ws;
    float* gi_f  = ws;                       // 8192*384
    float* gi_b  = gi_f + 3145728;           // 8192*384
    float* gie   = gi_b + 3145728;           // 8192*96
    float* swe   = gie + 786432;             // 8192*64 (hid_pre e-part)
    float* s_seq = swe + 524288;             // 8192*256
    float* h_seq = s_seq + 2097152;          // 8192*32 (unused slot, kept for layout)
    unsigned* pk   = (unsigned*)(h_seq + 262144);  // 49152 dwords (gru f16 B-frags)
    unsigned* pk_e = pk + 49152;                   // 1536 dwords (ctrl f16 pairs)
    (void)h_seq;

    float* out       = (float*)d_out;
    float* out_logit = out;                  // 147456
    float* out_mu    = out + 147456;         // 65536
    float* out_lv    = out + 212992;         // 65536
    float* out_beta  = out + 278528;         // 8192
    float* out_z     = out + 286720;         // 65536

    // gi projections + weight pack in one launch (y==24 row = pack)
    gemm_gi<<<dim3(128, 25), 256, 0, stream>>>(e, wih_f, bih_f, gi_f, wih_b, bih_b, gi_b,
                                               whh_f, whh_b, whh_e, pk, pk_e);
    // GRU recurrence (MFMA, 4-wave form) fused with gie/swe e-projections
    gru_fused<<<672, 256, 0, stream>>>(gi_f, gi_b, pk, bhh_f, bhh_b, s_seq,
                                       e, wih_e, bih_e, gie, sw1_w, sw1_b, swe);
    // add s-part of controller GRU input projection
    gemm_k<<<dim3(128, 3), 256, 0, stream>>>(s_seq, 256, wih_e + 256, 512, nullptr, gie, 96, 96, 1);
    // fused controller: reg-resident producer + u-decoupled consumer
    ctrl_fused<<<16, 128, 0, stream>>>(gie, pk_e, bhh_e, mu_w, mu_b, lv_w, lv_b,
                                       sw1_w, sw2_w, sw2_b, swe, eps,
                                       out_mu, out_lv, out_beta, out_z);
    // decoder hypernet + perturbation + LN + head
    decoder_final<<<1024, 256, 0, stream>>>(e, out_z, dec1_w, dec1_b, dec2_w, dec2_b,
                                            ln_g, ln_b, head_w, head_b, out_logit);
}

// Round 11
// 884.206 us; speedup vs baseline: 1.3469x; 1.3469x over previous
//
#include <hip/hip_runtime.h>

#define TT 512
#define BB 16
#define DD 256
#define HHH 128
#define GG 32
#define ZZ 8
#define RR_ 16
#define NAA 18

typedef _Float16 h2v __attribute__((ext_vector_type(2)));
typedef __attribute__((ext_vector_type(4))) float f4;
typedef __attribute__((ext_vector_type(4))) int i4;

__device__ __forceinline__ float sigmoid_(float x) { return 1.f / (1.f + __expf(-x)); }
__device__ __forceinline__ float tanh_(float x) { float e = __expf(2.f * x); return 1.f - 2.f / (e + 1.f); }
__device__ __forceinline__ float dot4(float4 a, float4 b) {
    return a.x * b.x + a.y * b.y + a.z * b.z + a.w * b.w;
}
__device__ __forceinline__ h2v u2h2(unsigned u) { union { unsigned u; h2v h; } c; c.u = u; return c.h; }

// Workgroup barrier WITHOUT the vmcnt(0) drain __syncthreads carries.
// Safe when cross-wave data flows through LDS only: global stores retire in
// the background, prefetch loads keep their compiler-tracked vmcnt slack.
__device__ __forceinline__ void lds_barrier() {
    asm volatile("s_waitcnt lgkmcnt(0)" ::: "memory");
    __builtin_amdgcn_s_barrier();
}

// VALU-speed cross-lane add via DPP
template <int CTRL, int RM, int BM, bool BC>
__device__ __forceinline__ float dpp_add_f(float v) {
    return v + __int_as_float(__builtin_amdgcn_update_dpp(0, __float_as_int(v), CTRL, RM, BM, BC));
}
__device__ __forceinline__ float wave_sum_bcast(float p) {
    p = dpp_add_f<0x111, 0xf, 0xf, true>(p);
    p = dpp_add_f<0x112, 0xf, 0xf, true>(p);
    p = dpp_add_f<0x114, 0xf, 0xf, true>(p);
    p = dpp_add_f<0x118, 0xf, 0xf, true>(p);
    p = dpp_add_f<0x142, 0xa, 0xf, false>(p);
    p = dpp_add_f<0x143, 0xc, 0xf, false>(p);
    return __int_as_float(__builtin_amdgcn_readlane(__float_as_int(p), 63));
}
__device__ __forceinline__ float quad_sum(float v) {
    v = dpp_add_f<0xB1, 0xf, 0xf, true>(v);
    v = dpp_add_f<0x4E, 0xf, 0xf, true>(v);
    return v;
}
__device__ __forceinline__ float rdlane(float v, int l) {
    return __int_as_float(__builtin_amdgcn_readlane(__float_as_int(v), l));
}

// ---------------------------------------------------------------------------
// Generic tiled GEMM (256 thr): Out[p][n] (+)= bias[n] + A[p]·W[n]
// ---------------------------------------------------------------------------
__global__ __launch_bounds__(256) void gemm_k(
    const float* __restrict__ A, int K, const float* __restrict__ W, int ldw,
    const float* __restrict__ bias, float* __restrict__ Out, int ldout, int N, int accFlag)
{
    __shared__ float At[64][36];
    __shared__ float Wt[32][36];
    int row0 = blockIdx.x * 64, n0 = blockIdx.y * 32;
    int tid = threadIdx.x;
    int tx = tid & 15, ty = tid >> 4;
    float acc[4][2] = {};
    for (int k0 = 0; k0 < K; k0 += 32) {
        #pragma unroll
        for (int i = 0; i < 8; ++i) {
            int idx = tid + i * 256; int rr = idx >> 5, kk = idx & 31;
            At[rr][kk] = A[(size_t)(row0 + rr) * K + k0 + kk];
        }
        #pragma unroll
        for (int i = 0; i < 4; ++i) {
            int idx = tid + i * 256; int nn = idx >> 5, kk = idx & 31;
            Wt[nn][kk] = (n0 + nn < N) ? W[(size_t)(n0 + nn) * ldw + k0 + kk] : 0.f;
        }
        __syncthreads();
        #pragma unroll
        for (int kk = 0; kk < 32; kk += 4) {
            float4 w0 = *(const float4*)&Wt[tx][kk];
            float4 w1 = *(const float4*)&Wt[tx + 16][kk];
            #pragma unroll
            for (int rr = 0; rr < 4; ++rr) {
                float4 av = *(const float4*)&At[ty * 4 + rr][kk];
                acc[rr][0] += dot4(av, w0);
                acc[rr][1] += dot4(av, w1);
            }
        }
        __syncthreads();
    }
    #pragma unroll
    for (int cc = 0; cc < 2; ++cc) {
        int n = n0 + tx + cc * 16;
        if (n < N) {
            float badd = bias ? bias[n] : 0.f;
            #pragma unroll
            for (int rr = 0; rr < 4; ++rr) {
                int row = row0 + ty * 4 + rr;
                float v = acc[rr][cc] + badd;
                if (accFlag) Out[(size_t)row * ldout + n] += v;
                else         Out[(size_t)row * ldout + n] = v;
            }
        }
    }
}

// ---------------------------------------------------------------------------
// Both gi projections (fwd+bwd) + weight pack in ONE launch: grid (128, 25).
// y<12 -> fwd tiles; y<24 -> bwd tiles; y==24 -> pack whh_f/whh_b/whh_e to
// f16 (reads only weights, writes only pk/pk_e; both precede gru_fused).
// ---------------------------------------------------------------------------
__global__ __launch_bounds__(256) void gemm_gi(
    const float* __restrict__ A,
    const float* __restrict__ wf, const float* __restrict__ bf, float* __restrict__ of,
    const float* __restrict__ wb, const float* __restrict__ bb, float* __restrict__ ob,
    const float* __restrict__ whf, const float* __restrict__ whb,
    const float* __restrict__ whe,
    unsigned* __restrict__ pk, unsigned* __restrict__ pk_e)
{
    int y = blockIdx.y;
    if (y == 24) {
        // ---- pack region (was pack_w): 32768 threads x up-to-2 items ----
        for (int i = blockIdx.x * 256 + threadIdx.x; i < 50688; i += 32768) {
            if (i < 49152) {
                int dir = i / 24576; int r = i % 24576;
                int w = r / 3072;    int r2 = r % 3072;
                int T = r2 / 1024;   int r3 = r2 % 1024;
                int kt = r3 / 256;   int r4 = r3 % 256;
                int lane = r4 / 4;   int jd = r4 % 4;
                const float* wsrc = dir ? whb : whf;
                int row = T * 128 + 16 * w + (lane & 15);
                int k0 = kt * 32 + (lane >> 4) * 8 + 2 * jd;
                union { _Float16 h[2]; unsigned u; } c;
                c.h[0] = (_Float16)wsrc[row * 128 + k0];
                c.h[1] = (_Float16)wsrc[row * 128 + k0 + 1];
                pk[i] = c.u;
            } else {
                int ie = i - 49152;
                int s = ie / 384;  int rem = ie % 384;
                int k = rem / 12;  int e = rem % 12;
                int j = e / 4;     int m = e % 4;
                int row = j * 32 + k, k0 = 8 * s + 2 * m;
                union { _Float16 h[2]; unsigned u; } c;
                c.h[0] = (_Float16)whe[row * 32 + k0];
                c.h[1] = (_Float16)whe[row * 32 + k0 + 1];
                pk_e[ie] = c.u;
            }
        }
        return;
    }

    __shared__ float At[64][36];
    __shared__ float Wt[32][36];
    const float* W; const float* bias; float* Out; int n0;
    if (y < 12) { W = wf; bias = bf; Out = of; n0 = y * 32; }
    else        { W = wb; bias = bb; Out = ob; n0 = (y - 12) * 32; }
    int row0 = blockIdx.x * 64;
    int tid = threadIdx.x;
    int tx = tid & 15, ty = tid >> 4;
    float acc[4][2] = {};
    for (int k0 = 0; k0 < 256; k0 += 32) {
        #pragma unroll
        for (int i = 0; i < 8; ++i) {
            int idx = tid + i * 256; int rr = idx >> 5, kk = idx & 31;
            At[rr][kk] = A[(size_t)(row0 + rr) * 256 + k0 + kk];
        }
        #pragma unroll
        for (int i = 0; i < 4; ++i) {
            int idx = tid + i * 256; int nn = idx >> 5, kk = idx & 31;
            Wt[nn][kk] = W[(size_t)(n0 + nn) * 256 + k0 + kk];
        }
        __syncthreads();
        #pragma unroll
        for (int kk = 0; kk < 32; kk += 4) {
            float4 w0 = *(const float4*)&Wt[tx][kk];
            float4 w1 = *(const float4*)&Wt[tx + 16][kk];
            #pragma unroll
            for (int rr = 0; rr < 4; ++rr) {
                float4 av = *(const float4*)&At[ty * 4 + rr][kk];
                acc[rr][0] += dot4(av, w0);
                acc[rr][1] += dot4(av, w1);
            }
        }
        __syncthreads();
    }
    #pragma unroll
    for (int cc = 0; cc < 2; ++cc) {
        int n = n0 + tx + cc * 16;
        float badd = bias[n];
        #pragma unroll
        for (int rr = 0; rr < 4; ++rr) {
            int row = row0 + ty * 4 + rr;
            Out[(size_t)row * 384 + n] = acc[rr][cc] + badd;
        }
    }
}

// ---------------------------------------------------------------------------
// Fused dispatch (256 thr/block): blocks 0-31 = GRU scan, 4 waves per block
// (each wave owns TWO j-tiles = 24 MFMAs; epilogue on lanes<32).
// Blocks 32-415 = gie tiles; 416-671 = swe tiles (gemm_k-style 64x32 tiles).
// ---------------------------------------------------------------------------
struct __align__(16) SmGru { _Float16 hb[2][128]; };
struct __align__(16) SmGemm { float At[64][36]; float Wt[32][36]; };
union __align__(16) SmU { SmGru g; SmGemm m; };

__device__ __forceinline__ void gemm_tile256(
    const float* __restrict__ A, int K, const float* __restrict__ W, int ldw,
    const float* __restrict__ bias, float* __restrict__ Out, int ldout, int N,
    int row0, int n0, SmGemm& sm)
{
    int tid = threadIdx.x;
    int tx = tid & 15, ty = tid >> 4;
    float acc[4][2] = {};
    for (int k0 = 0; k0 < K; k0 += 32) {
        #pragma unroll
        for (int i = 0; i < 8; ++i) {
            int idx = tid + i * 256; int rr = idx >> 5, kk = idx & 31;
            sm.At[rr][kk] = A[(size_t)(row0 + rr) * K + k0 + kk];
        }
        #pragma unroll
        for (int i = 0; i < 4; ++i) {
            int idx = tid + i * 256; int nn = idx >> 5, kk = idx & 31;
            sm.Wt[nn][kk] = (n0 + nn < N) ? W[(size_t)(n0 + nn) * ldw + k0 + kk] : 0.f;
        }
        __syncthreads();
        #pragma unroll
        for (int kk = 0; kk < 32; kk += 4) {
            float4 w0 = *(const float4*)&sm.Wt[tx][kk];
            float4 w1 = *(const float4*)&sm.Wt[tx + 16][kk];
            #pragma unroll
            for (int rr = 0; rr < 4; ++rr) {
                float4 av = *(const float4*)&sm.At[ty * 4 + rr][kk];
                acc[rr][0] += dot4(av, w0);
                acc[rr][1] += dot4(av, w1);
            }
        }
        __syncthreads();
    }
    #pragma unroll
    for (int cc = 0; cc < 2; ++cc) {
        int n = n0 + tx + cc * 16;
        if (n < N) {
            float badd = bias[n];
            #pragma unroll
            for (int rr = 0; rr < 4; ++rr)
                Out[(size_t)(row0 + ty * 4 + rr) * ldout + n] = acc[rr][cc] + badd;
        }
    }
}

__global__ __launch_bounds__(256, 2) void gru_fused(
    const float* __restrict__ gi_f, const float* __restrict__ gi_b,
    const unsigned* __restrict__ pk,
    const float* __restrict__ bhh_f, const float* __restrict__ bhh_b,
    float* __restrict__ s_seq,
    const float* __restrict__ e,
    const float* __restrict__ wih_e, const float* __restrict__ bih_e, float* __restrict__ gie,
    const float* __restrict__ sw1_w, const float* __restrict__ sw1_b, float* __restrict__ swe)
{
    __shared__ SmU sm;
    int bx = blockIdx.x;
    if (bx >= 416) {
        int t = bx - 416;
        gemm_tile256(e, 256, sw1_w, 296, sw1_b, swe, 64, 64, (t & 127) * 64, (t >> 7) * 32, sm.m);
        return;
    }
    if (bx >= 32) {
        int t = bx - 32;
        gemm_tile256(e, 256, wih_e, 512, bih_e, gie, 96, 96, (t & 127) * 64, (t >> 7) * 32, sm.m);
        return;
    }

    // ---------------- GRU (MFMA body, 4-wave form) ----------------
    int dir = bx >> 4, b = bx & 15;
    const float* gi  = dir ? gi_b  : gi_f;
    const float* bhh = dir ? bhh_b : bhh_f;
    int tid = threadIdx.x;
    int w = tid >> 6;          // 0..3
    int lane = tid & 63;
    int quad = lane >> 4;
    int j = 32 * w + (lane & 31);   // epilogue j (valid for lane<32)

    // B-frags: 2 j-tiles per wave (tile idx = 2w+tt), unchanged pk layout.
    i4 bf[2][3][4];
    #pragma unroll
    for (int tt = 0; tt < 2; ++tt)
        #pragma unroll
        for (int T = 0; T < 3; ++T)
            #pragma unroll
            for (int kt = 0; kt < 4; ++kt)
                bf[tt][T][kt] = *(const i4*)(pk + (size_t)((((dir * 8 + 2 * w + tt) * 3 + T) * 4 + kt) * 64 + lane) * 4);
    #pragma unroll
    for (int tt = 0; tt < 2; ++tt)
        #pragma unroll
        for (int T = 0; T < 3; ++T)
            #pragma unroll
            for (int kt = 0; kt < 4; ++kt)
                asm volatile("" : "+a"(bf[tt][T][kt]));

    if (tid < 128) sm.g.hb[0][tid] = (_Float16)0.f;

    float bhr = 0.f, bhz = 0.f, bhn = 0.f;
    float gra = 0.f, gza = 0.f, gna = 0.f;
    float grb = 0.f, gzb = 0.f, gnb = 0.f;
    float hreg = 0.f;
    if (lane < 32) {
        bhr = bhh[j]; bhz = bhh[128 + j]; bhn = bhh[256 + j];
        int t0 = dir ? 511 : 0;
        int t1 = dir ? 510 : 1;
        size_t p0 = (size_t)(b * TT + t0) * 384;
        size_t p1 = (size_t)(b * TT + t1) * 384;
        gra = gi[p0 + j]; gza = gi[p0 + 128 + j]; gna = gi[p0 + 256 + j];
        grb = gi[p1 + j]; gzb = gi[p1 + 128 + j]; gnb = gi[p1 + 256 + j];
    }
    __syncthreads();

    int cur = 0;
    auto body = [&](int step, float& gr, float& gz, float& gn) {
        i4 af[4];
        #pragma unroll
        for (int kt = 0; kt < 4; ++kt)
            af[kt] = *(const i4*)(&sm.g.hb[cur][kt * 32 + quad * 8]);
        f4 accr0 = {0.f, 0.f, 0.f, 0.f}, accr1 = {0.f, 0.f, 0.f, 0.f};
        f4 accz0 = {0.f, 0.f, 0.f, 0.f}, accz1 = {0.f, 0.f, 0.f, 0.f};
        f4 accn0 = {0.f, 0.f, 0.f, 0.f}, accn1 = {0.f, 0.f, 0.f, 0.f};
        // anchored pre-MFMA fence (VALU-write -> MFMA SrcC hazard)
        asm volatile("s_nop 3" : "+v"(accr0), "+v"(accz0), "+v"(accn0),
                                 "+v"(accr1), "+v"(accz1), "+v"(accn1));
        #pragma unroll
        for (int kt = 0; kt < 4; ++kt) {
            asm volatile("v_mfma_f32_16x16x32_f16 %0, %1, %2, %0" : "+v"(accr0) : "v"(af[kt]), "a"(bf[0][0][kt]));
            asm volatile("v_mfma_f32_16x16x32_f16 %0, %1, %2, %0" : "+v"(accz0) : "v"(af[kt]), "a"(bf[0][1][kt]));
            asm volatile("v_mfma_f32_16x16x32_f16 %0, %1, %2, %0" : "+v"(accn0) : "v"(af[kt]), "a"(bf[0][2][kt]));
            asm volatile("v_mfma_f32_16x16x32_f16 %0, %1, %2, %0" : "+v"(accr1) : "v"(af[kt]), "a"(bf[1][0][kt]));
            asm volatile("v_mfma_f32_16x16x32_f16 %0, %1, %2, %0" : "+v"(accz1) : "v"(af[kt]), "a"(bf[1][1][kt]));
            asm volatile("v_mfma_f32_16x16x32_f16 %0, %1, %2, %0" : "+v"(accn1) : "v"(af[kt]), "a"(bf[1][2][kt]));
        }
        // anchored post-MFMA fence (no acc read hoists above it)
        asm volatile("s_nop 7\n\ts_nop 7" : "+v"(accr0), "+v"(accz0), "+v"(accn0),
                                            "+v"(accr1), "+v"(accz1), "+v"(accn1));
        if (lane < 32) {
            int t = dir ? (511 - step) : step;
            int p = b * TT + t;
            bool hi = lane >= 16;          // tile select within the wave's 32 j
            float ar = hi ? accr1[0] : accr0[0];
            float az = hi ? accz1[0] : accz0[0];
            float an = hi ? accn1[0] : accn0[0];
            float r = sigmoid_(gr + bhr + ar);
            float z = sigmoid_(gz + bhz + az);
            float n = tanh_(gn + r * (bhn + an));
            float hn = (1.f - z) * n + z * hreg;
            hreg = hn;
            sm.g.hb[cur ^ 1][j] = (_Float16)hn;
            s_seq[(size_t)p * 256 + dir * 128 + j] = hn;
            int s2 = step + 2;
            int tp = (s2 < 512) ? (dir ? (511 - s2) : s2) : t;
            size_t p2 = (size_t)(b * TT + tp) * 384;
            gr = gi[p2 + j]; gz = gi[p2 + 128 + j]; gn = gi[p2 + 256 + j];
        }
        lds_barrier();
        cur ^= 1;
    };

    for (int step = 0; step < 512; step += 2) {
        body(step,     gra, gza, gna);
        body(step + 1, grb, gzb, gnb);
    }
}

// ---------------------------------------------------------------------------
// Fused controller, 16-steps-per-phase pipeline (33 barriers). 32-slot LDS
// ring so the lagging consumer's 16 slots are never overwritten mid-phase.
// Wave 0 = GRU h-scan producer (intra-phase self-deps need only lgkmcnt);
// wave 1 = mu/lv/switching/z consumer, one phase behind. [R6/R8-measured
// 259us. Falsified alternatives: 2-batch ILP (R7, 503us — exec-mask-sealed
// regions), reg-resident h via bpermute (R10, 563us — 18 LDS-crossbar ops
// on the serial path are worse than one write->read round-trip).]
// ---------------------------------------------------------------------------
__global__ __launch_bounds__(128, 1) void ctrl_fused(
    const float* __restrict__ gie, const unsigned* __restrict__ pk_e,
    const float* __restrict__ bhh_e,
    const float* __restrict__ mu_w, const float* __restrict__ mu_b,
    const float* __restrict__ lv_w, const float* __restrict__ lv_b,
    const float* __restrict__ sw1_w, const float* __restrict__ sw2_w,
    const float* __restrict__ sw2_b,
    const float* __restrict__ swe,      // hid_pre e-part (B*T, 64)
    const float* __restrict__ eps,      // (B*T, 8)
    float* __restrict__ out_mu, float* __restrict__ out_lv,
    float* __restrict__ beta_o, float* __restrict__ z_o)
{
    int b = blockIdx.x;
    int tid = threadIdx.x;
    int wid = tid >> 6;
    int lane = tid & 63;
    int pbase = b * TT;

    __shared__ __align__(16) _Float16 hb[32][32];   // f16 ring (producer fdot2)
    __shared__ __align__(16) float    hf[32][32];   // f32 ring (consumer math)

    // ---- producer state (wave 0): 2-way K split, single wave ----
    int k = lane >> 1, s2 = lane & 1;
    unsigned wg[24];
    float bhr = 0.f, bhz = 0.f, bhn = 0.f, hreg = 0.f;
    float g1[16] = {}, g2[16] = {}, g3[16] = {};
    if (wid == 0) {
        #pragma unroll
        for (int ss = 0; ss < 2; ++ss) {
            const uint4* wp = (const uint4*)(pk_e + ((size_t)((2 * s2 + ss) * 32) + k) * 12);
            #pragma unroll
            for (int i = 0; i < 3; ++i) {
                uint4 u = wp[i];
                wg[12 * ss + 4 * i + 0] = u.x;
                wg[12 * ss + 4 * i + 1] = u.y;
                wg[12 * ss + 4 * i + 2] = u.z;
                wg[12 * ss + 4 * i + 3] = u.w;
            }
        }
        if (lane < 32) hb[31][lane] = (_Float16)0.f;
        if (s2 == 0) {
            bhr = bhh_e[k]; bhz = bhh_e[32 + k]; bhn = bhh_e[64 + k];
            #pragma unroll
            for (int i = 0; i < 16; ++i) {
                size_t p = (size_t)(pbase + i) * 96;
                g1[i] = gie[p + k]; g2[i] = gie[p + 32 + k]; g3[i] = gie[p + 64 + k];
            }
        }
    }

    // ---- consumer state (wave 1) ----
    int x = lane >> 3, kind = (lane >> 2) & 1, s = lane & 3;
    float4 swh4[8];
    float4 wz0v = {0,0,0,0}, wz1v = {0,0,0,0}, mlw0 = {0,0,0,0}, mlw1 = {0,0,0,0};
    float w2 = 0.f, sb2 = 0.f, mlb = 0.f;
    float4 zr0 = {0.f, 0.f, 0.f, 0.f}, zr1 = {0.f, 0.f, 0.f, 0.f};
    float hp[16] = {}, ep[16] = {};
    if (wid == 1) {
        #pragma unroll
        for (int i = 0; i < 8; ++i)
            swh4[i] = *(const float4*)(sw1_w + (size_t)lane * 296 + 256 + 4 * i);
        wz0v = *(const float4*)(sw1_w + (size_t)lane * 296 + 288);
        wz1v = *(const float4*)(sw1_w + (size_t)lane * 296 + 292);
        w2 = sw2_w[lane];
        sb2 = sw2_b[0];
        const float* mw = kind ? lv_w : mu_w;
        mlw0 = *(const float4*)(mw + x * 32 + 8 * s);
        mlw1 = *(const float4*)(mw + x * 32 + 8 * s + 4);
        mlb = kind ? lv_b[x] : mu_b[x];
        #pragma unroll
        for (int i = 0; i < 16; ++i) {
            hp[i] = swe[(size_t)(pbase + i) * 64 + lane];
            ep[i] = eps[(size_t)(pbase + i) * 8 + x];
        }
    }
    __syncthreads();

    auto prod_step = [&](int t, float& ga, float& gb, float& gc) {
        const uint4* hv = (const uint4*)(&hb[(t - 1) & 31][16 * s2]);
        uint4 hA = hv[0], hB = hv[1];
        unsigned hw[8] = {hA.x, hA.y, hA.z, hA.w, hB.x, hB.y, hB.z, hB.w};
        float a0 = 0.f, a1 = 0.f, a2 = 0.f, c0 = 0.f, c1 = 0.f, c2 = 0.f;
        #pragma unroll
        for (int m = 0; m < 4; ++m) {
            a0 = __builtin_amdgcn_fdot2(u2h2(wg[m]),      u2h2(hw[m]),     a0, false);
            a1 = __builtin_amdgcn_fdot2(u2h2(wg[4 + m]),  u2h2(hw[m]),     a1, false);
            a2 = __builtin_amdgcn_fdot2(u2h2(wg[8 + m]),  u2h2(hw[m]),     a2, false);
            c0 = __builtin_amdgcn_fdot2(u2h2(wg[12 + m]), u2h2(hw[4 + m]), c0, false);
            c1 = __builtin_amdgcn_fdot2(u2h2(wg[16 + m]), u2h2(hw[4 + m]), c1, false);
            c2 = __builtin_amdgcn_fdot2(u2h2(wg[20 + m]), u2h2(hw[4 + m]), c2, false);
        }
        a0 += c0; a1 += c1; a2 += c2;
        a0 = dpp_add_f<0xB1, 0xf, 0xf, true>(a0);   // pair sum across s2
        a1 = dpp_add_f<0xB1, 0xf, 0xf, true>(a1);
        a2 = dpp_add_f<0xB1, 0xf, 0xf, true>(a2);
        if (s2 == 0) {
            float r = sigmoid_(ga + bhr + a0);
            float z = sigmoid_(gb + bhz + a1);
            float n = tanh_(gc + r * (bhn + a2));
            float hn = (1.f - z) * n + z * hreg;
            hreg = hn;
            hb[t & 31][k] = (_Float16)hn;
            hf[t & 31][k] = hn;
            int t16 = (t + 16 < 512) ? (t + 16) : t;
            size_t p2 = (size_t)(pbase + t16) * 96;
            ga = gie[p2 + k]; gb = gie[p2 + 32 + k]; gc = gie[p2 + 64 + k];
        }
    };

    auto cons_step = [&](int t, float& hpi, float& epi) {
        int sl = t & 31;
        const float4* hv4 = (const float4*)(&hf[sl][0]);
        float4 h0 = hv4[0], h1 = hv4[1], h2 = hv4[2], h3 = hv4[3];
        float4 h4 = hv4[4], h5 = hv4[5], h6 = hv4[6], h7 = hv4[7];
        // z-independent: switching-h dot, tree-split into 4 chains
        float d0 = dot4(swh4[0], h0) + dot4(swh4[1], h1);
        float d1 = dot4(swh4[2], h2) + dot4(swh4[3], h3);
        float d2 = dot4(swh4[4], h4) + dot4(swh4[5], h5);
        float d3 = dot4(swh4[6], h6) + dot4(swh4[7], h7);
        float hsum = (d0 + d1) + (d2 + d3);
        // z-independent: mu/lv quarter-dot + candidate
        float4 hs0 = *(const float4*)(&hf[sl][8 * s]);
        float4 hs1 = *(const float4*)(&hf[sl][8 * s + 4]);
        float pacc = quad_sum(dot4(mlw0, hs0) + dot4(mlw1, hs1));
        float v = pacc + mlb;
        float other = __int_as_float(__builtin_amdgcn_ds_swizzle(__float_as_int(v), 0x101F)); // xor 4
        float muv = kind ? other : v;
        float lvv = kind ? v : other;
        float cand = muv + __expf(0.5f * lvv) * epi;
        // broadcast 8 candidates to SGPRs (z-independent; completes early)
        float sc0 = rdlane(cand, 0),  sc1 = rdlane(cand, 8);
        float sc2 = rdlane(cand, 16), sc3 = rdlane(cand, 24);
        float sc4 = rdlane(cand, 32), sc5 = rdlane(cand, 40);
        float sc6 = rdlane(cand, 48), sc7 = rdlane(cand, 56);
        // z-serial chain
        float az = dot4(wz0v, zr0) + dot4(wz1v, zr1);
        float a = (hpi + hsum) + az;
        float hid = tanh_(a);
        float beta = sigmoid_(wave_sum_bcast(w2 * hid) + sb2);
        float omb = 1.f - beta;
        zr0.x = beta * sc0 + omb * zr0.x; zr0.y = beta * sc1 + omb * zr0.y;
        zr0.z = beta * sc2 + omb * zr0.z; zr0.w = beta * sc3 + omb * zr0.w;
        zr1.x = beta * sc4 + omb * zr1.x; zr1.y = beta * sc5 + omb * zr1.y;
        zr1.z = beta * sc6 + omb * zr1.z; zr1.w = beta * sc7 + omb * zr1.w;
        int p = pbase + t;
        if (lane == 0) {
            beta_o[p] = beta;
            *(float4*)(z_o + (size_t)p * 8)     = zr0;
            *(float4*)(z_o + (size_t)p * 8 + 4) = zr1;
        }
        if ((lane & 7) == 0) out_mu[(size_t)p * 8 + x] = muv;
        if ((lane & 7) == 4) out_lv[(size_t)p * 8 + x] = lvv;
        int t16 = (t + 16 < 512) ? (t + 16) : t;
        hpi = swe[(size_t)(pbase + t16) * 64 + lane];
        epi = eps[(size_t)(pbase + t16) * 8 + x];
    };

    // 33 phases: producer active in 0..31, consumer in 1..32 (lags 1 phase)
    for (int ph = 0; ph < 33; ++ph) {
        if (wid == 0) {
            if (ph < 32) {
                int t0 = ph * 16;
                #pragma unroll
                for (int i = 0; i < 16; ++i)
                    prod_step(t0 + i, g1[i], g2[i], g3[i]);
            }
        } else {
            if (ph >= 1) {
                int t0 = (ph - 1) * 16;
                #pragma unroll
                for (int i = 0; i < 16; ++i)
                    cons_step(t0 + i, hp[i], ep[i]);
            }
        }
        lds_barrier();
    }
}

// ---------------------------------------------------------------------------
// Decoder hypernet + rank-R perturbation + LayerNorm + head. P=8/WG.
// ---------------------------------------------------------------------------
__global__ __launch_bounds__(256, 3) void decoder_final(
    const float* __restrict__ e_seq, const float* __restrict__ z_o,
    const float* __restrict__ dec1_w, const float* __restrict__ dec1_b,
    const float* __restrict__ dec2_w, const float* __restrict__ dec2_b,
    const float* __restrict__ ln_g, const float* __restrict__ ln_b,
    const float* __restrict__ head_w, const float* __restrict__ head_b,
    float* __restrict__ logits)
{
    __shared__ __align__(16) float e_l[8][256];
    __shared__ __align__(16) float hmid[8][32];
    __shared__ float zl[8][8];
    __shared__ float tmpw[8][16];
    __shared__ __align__(16) float partb[2048];
    __shared__ float red1[8][16];
    __shared__ float red2[8][16];
    __shared__ float stats[8][2];
    int tid = threadIdx.x;
    int p0 = blockIdx.x * 8;

    {
        const float4* eg = (const float4*)(e_seq + (size_t)p0 * 256);
        float4* el4 = (float4*)&e_l[0][0];
        el4[tid] = eg[tid];
        el4[tid + 256] = eg[tid + 256];
        if (tid < 64) ((float*)zl)[tid] = z_o[p0 * 8 + tid];
    }
    __syncthreads();
    {
        int pp = tid >> 5, g = tid & 31;
        float a = dec1_b[g];
        #pragma unroll
        for (int x = 0; x < 8; ++x) a += dec1_w[g * 8 + x] * zl[pp][x];
        hmid[pp][g] = tanh_(a);
    }
    __syncthreads();
    // ---- pass B: tmp[pp][r] = sum_d Bm[d,r]*e[d]
    {
        int r = tid & 15, dgrp = tid >> 4;
        float acc[8];
        #pragma unroll
        for (int pp = 0; pp < 8; ++pp) acc[pp] = 0.f;
        for (int iblk = 0; iblk < 8; ++iblk) {
            float4 wr[2][8]; float wb[2]; int dd[2];
            #pragma unroll
            for (int ii = 0; ii < 2; ++ii) {
                int d = dgrp + 16 * (iblk * 2 + ii);
                dd[ii] = d;
                int row = 4096 + d * 16 + r;
                const float4* wp = (const float4*)(dec2_w + (size_t)row * 32);
                #pragma unroll
                for (int g = 0; g < 8; ++g) wr[ii][g] = wp[g];
                wb[ii] = dec2_b[row];
            }
            #pragma unroll 1
            for (int pp = 0; pp < 8; ++pp) {
                const float4* hv = (const float4*)hmid[pp];
                float b0 = wb[0], b1 = wb[1];
                #pragma unroll
                for (int g = 0; g < 8; ++g) {
                    float4 hh = hv[g];
                    b0 += dot4(wr[0][g], hh);
                    b1 += dot4(wr[1][g], hh);
                }
                acc[pp] += b0 * e_l[pp][dd[0]] + b1 * e_l[pp][dd[1]];
            }
        }
        #pragma unroll
        for (int pp = 0; pp < 8; ++pp) partb[(pp * 16 + r) * 16 + dgrp] = acc[pp];
    }
    __syncthreads();
    if (tid < 128) {
        int pp = tid >> 4, rr = tid & 15;
        float s = 0.f;
        #pragma unroll
        for (int dg = 0; dg < 16; ++dg) s += partb[(pp * 16 + rr) * 16 + dg];
        tmpw[pp][rr] = s;
    }
    __syncthreads();
    // ---- pass A
    {
        int d = tid;
        float po[8];
        #pragma unroll
        for (int pp = 0; pp < 8; ++pp) po[pp] = e_l[pp][d];
        for (int rblk = 0; rblk < 8; ++rblk) {
            float4 wr[2][8]; float wb[2];
            #pragma unroll
            for (int ii = 0; ii < 2; ++ii) {
                int row = d * 16 + rblk * 2 + ii;
                const float4* wp = (const float4*)(dec2_w + (size_t)row * 32);
                #pragma unroll
                for (int g = 0; g < 8; ++g) wr[ii][g] = wp[g];
                wb[ii] = dec2_b[row];
            }
            #pragma unroll 1
            for (int pp = 0; pp < 8; ++pp) {
                const float4* hv = (const float4*)hmid[pp];
                float a0 = wb[0], a1 = wb[1];
                #pragma unroll
                for (int g = 0; g < 8; ++g) {
                    float4 hh = hv[g];
                    a0 += dot4(wr[0][g], hh);
                    a1 += dot4(wr[1][g], hh);
                }
                po[pp] += a0 * tmpw[pp][rblk * 2] + a1 * tmpw[pp][rblk * 2 + 1];
            }
        }
        #pragma unroll
        for (int pp = 0; pp < 8; ++pp) partb[pp * 256 + d] = po[pp];
    }
    __syncthreads();
    if (tid < 128) {
        int pp = tid >> 4, c = tid & 15;
        float s = 0.f, s2 = 0.f;
        #pragma unroll
        for (int i = 0; i < 16; ++i) { float v = partb[pp * 256 + c * 16 + i]; s += v; s2 += v * v; }
        red1[pp][c] = s; red2[pp][c] = s2;
    }
    __syncthreads();
    if (tid < 8) {
        float s = 0.f, s2 = 0.f;
        #pragma unroll
        for (int c = 0; c < 16; ++c) { s += red1[tid][c]; s2 += red2[tid][c]; }
        float mean = s * (1.f / 256.f);
        float var = s2 * (1.f / 256.f) - mean * mean;
        stats[tid][0] = mean;
        stats[tid][1] = rsqrtf(var + 1e-5f);
    }
    __syncthreads();
    {
        int d = tid;
        float g = ln_g[d], bln = ln_b[d];
        #pragma unroll
        for (int pp = 0; pp < 8; ++pp) {
            float v = (partb[pp * 256 + d] - stats[pp][0]) * stats[pp][1];
            partb[pp * 256 + d] = v * g + bln;
        }
    }
    __syncthreads();
    if (tid < 144) {
        int pp = tid / 18, na = tid - pp * 18;
        float a = head_b[na];
        for (int d2 = 0; d2 < 256; ++d2)
            a += partb[pp * 256 + d2] * head_w[na * 256 + d2];
        logits[(size_t)(p0 + pp) * 18 + na] = a;
    }
}

// ---------------------------------------------------------------------------
extern "C" void kernel_launch(void* const* d_in, const int* in_sizes, int n_in,
                              void* d_out, int out_size, void* d_ws, size_t ws_size,
                              hipStream_t stream) {
    (void)in_sizes; (void)n_in; (void)out_size; (void)ws_size;
    const float* e     = (const float*)d_in[0];
    const float* eps   = (const float*)d_in[1];
    const float* wih_f = (const float*)d_in[2];
    const float* whh_f = (const float*)d_in[3];
    const float* bih_f = (const float*)d_in[4];
    const float* bhh_f = (const float*)d_in[5];
    const float* wih_b = (const float*)d_in[6];
    const float* whh_b = (const float*)d_in[7];
    const float* bih_b = (const float*)d_in[8];
    const float* bhh_b = (const float*)d_in[9];
    const float* wih_e = (const float*)d_in[10];
    const float* whh_e = (const float*)d_in[11];
    const float* bih_e = (const float*)d_in[12];
    const float* bhh_e = (const float*)d_in[13];
    const float* mu_w  = (const float*)d_in[14];
    const float* mu_b  = (const float*)d_in[15];
    const float* lv_w  = (const float*)d_in[16];
    const float* lv_b  = (const float*)d_in[17];
    const float* sw1_w = (const float*)d_in[18];
    const float* sw1_b = (const float*)d_in[19];
    const float* sw2_w = (const float*)d_in[20];
    const float* sw2_b = (const float*)d_in[21];
    const float* dec1_w = (const float*)d_in[22];
    const float* dec1_b = (const float*)d_in[23];
    const float* dec2_w = (const float*)d_in[24];
    const float* dec2_b = (const float*)d_in[25];
    const float* ln_g  = (const float*)d_in[26];
    const float* ln_b  = (const float*)d_in[27];
    const float* head_w = (const float*)d_in[28];
    const float* head_b = (const float*)d_in[29];

    float* ws    = (float*)d_ws;
    float* gi_f  = ws;                       // 8192*384
    float* gi_b  = gi_f + 3145728;           // 8192*384
    float* gie   = gi_b + 3145728;           // 8192*96
    float* swe   = gie + 786432;             // 8192*64 (hid_pre e-part)
    float* s_seq = swe + 524288;             // 8192*256
    float* h_seq = s_seq + 2097152;          // 8192*32 (unused slot, kept for layout)
    unsigned* pk   = (unsigned*)(h_seq + 262144);  // 49152 dwords (gru f16 B-frags)
    unsigned* pk_e = pk + 49152;                   // 1536 dwords (ctrl f16 pairs)
    (void)h_seq;

    float* out       = (float*)d_out;
    float* out_logit = out;                  // 147456
    float* out_mu    = out + 147456;         // 65536
    float* out_lv    = out + 212992;         // 65536
    float* out_beta  = out + 278528;         // 8192
    float* out_z     = out + 286720;         // 65536

    // gi projections + weight pack in one launch (y==24 row = pack)
    gemm_gi<<<dim3(128, 25), 256, 0, stream>>>(e, wih_f, bih_f, gi_f, wih_b, bih_b, gi_b,
                                               whh_f, whh_b, whh_e, pk, pk_e);
    // GRU recurrence (MFMA, 4-wave form) fused with gie/swe e-projections
    gru_fused<<<672, 256, 0, stream>>>(gi_f, gi_b, pk, bhh_f, bhh_b, s_seq,
                                       e, wih_e, bih_e, gie, sw1_w, sw1_b, swe);
    // add s-part of controller GRU input projection
    gemm_k<<<dim3(128, 3), 256, 0, stream>>>(s_seq, 256, wih_e + 256, 512, nullptr, gie, 96, 96, 1);
    // fused controller: h-scan + mu/lv/switching heads + z-scan (16-step phases)
    ctrl_fused<<<16, 128, 0, stream>>>(gie, pk_e, bhh_e, mu_w, mu_b, lv_w, lv_b,
                                       sw1_w, sw2_w, sw2_b, swe, eps,
                                       out_mu, out_lv, out_beta, out_z);
    // decoder hypernet + perturbation + LN + head
    decoder_final<<<1024, 256, 0, stream>>>(e, out_z, dec1_w, dec1_b, dec2_w, dec2_b,
                                            ln_g, ln_b, head_w, head_b, out_logit);
}